// Round 3
// baseline (3592.589 us; speedup 1.0000x reference)
//
#include <hip/hip_runtime.h>

// B=32768, K=16, D=256, H=2, HD=128
#define Bsz 32768
#define BR  16           // rows per block
#define SCALE 0.08838834764831845f   // 1/sqrt(128)

// ---------------------------------------------------------------------------
// Prep: fp32 weights in ws. All [N][256] row-major.
//   W1f rows 0..511  : M_h[k][m] = sum_d Wq[h*128+d][k]*Wk[h*128+d][m]  (n=h*256+m)
//   W1f rows 512..639: Wc
//   W2f = Wv (256 rows), W3f = Wx (128 rows)
// ws use: (640+256+128)*256*4 = 1 MiB.
// ---------------------------------------------------------------------------
__global__ void prep_kernel(const float* __restrict__ Wq, const float* __restrict__ Wk,
                            const float* __restrict__ Wv, const float* __restrict__ Wc,
                            const float* __restrict__ Wx, float* __restrict__ wsf){
  float* W1f = wsf;                 // 640*256
  float* W2f = wsf + 640*256;       // 256*256
  float* W3f = W2f + 256*256;       // 128*256
  const int n = blockIdx.x;
  const int k = threadIdx.x;
  if (n < 512){
    const int h = n >> 8, m = n & 255;
    const float* wq = Wq + h*128*256 + k;   // column k (coalesced over k)
    const float* wk = Wk + h*128*256 + m;   // broadcast
    float s = 0.f;
    for (int d = 0; d < 128; ++d) s += wq[d*256] * wk[d*256];
    W1f[n*256 + k] = s;
  } else if (n < 640){
    W1f[n*256 + k] = Wc[(n-512)*256 + k];
  } else if (n < 896){
    const int r = n - 640; W2f[r*256 + k] = Wv[r*256 + k];
  } else {
    const int r = n - 896; W3f[r*256 + k] = Wx[r*256 + k];
  }
}

// ---------------------------------------------------------------------------
// Fused main kernel — ALL fp32 VALU (diagnostic bisect: no bf16, no MFMA).
// 16 rows/block, 256 threads (4 waves).
// LDS: s_c    f32 [16][260]: center (phases 0-A), then ctx (C-D)
//      s_ctil f32 [16][520]: ctil (A-B), then agg (B-C), then ctx_n (D-E)
// ---------------------------------------------------------------------------
__global__ __launch_bounds__(256, 3) void fused_kernel(
    const float* __restrict__ center, const float* __restrict__ nbr,
    const float* __restrict__ ew, const float* __restrict__ gamma,
    const float* __restrict__ beta, const float* __restrict__ Wall,
    float* __restrict__ out)
{
  __shared__ __align__(16) float s_c[BR*260];
  __shared__ __align__(16) float s_ctil[BR*520];

  const int tid  = threadIdx.x;
  const int wid  = tid >> 6;
  const int lane = tid & 63;
  const int b0   = blockIdx.x * BR;

  const float* W1f = Wall;              // 640*256
  const float* W2f = Wall + 640*256;    // 256*256
  const float* W3f = W2f + 256*256;     // 128*256

  const int tr = tid >> 4;     // 0..15 (row this thread owns in GEMM phases)
  const int tc = tid & 15;     // 0..15 (col-within-chunk)

  // ---- stage center tile -> fp32 LDS ----
  {
    const float* cp = center + ((long)(b0 + tr) << 8) + tc*16;
    #pragma unroll
    for (int it = 0; it < 4; ++it)
      *(float4*)&s_c[tr*260 + tc*16 + it*4] = *(const float4*)(cp + it*4);
  }
  __syncthreads();

  // ---- Phase A: [16x256] @ [256x640] -> ctil (LDS) + out-left (global) ----
  {
    for (int t = 0; t < 40; ++t){
      const int col = t*16 + tc;            // 0..639
      const float* wp = W1f + col*256;
      float acc = 0.f;
      #pragma unroll 8
      for (int e = 0; e < 256; e += 4){
        float4 cv = *(const float4*)&s_c[tr*260 + e];
        float4 wv = *(const float4*)(wp + e);
        acc += cv.x*wv.x + cv.y*wv.y + cv.z*wv.z + cv.w*wv.w;
      }
      if (col < 512) s_ctil[tr*520 + col] = acc;
      else           out[((long)(b0 + tr) << 8) + (col - 512)] = acc;
    }
  }
  __syncthreads();

  // ---- Phase B: attention (one wave per 4 rows); agg fp32 into s_ctil ----
  {
    #pragma unroll 1
    for (int rr = 0; rr < 4; ++rr){
      const int r = wid*4 + rr;
      const long b = b0 + r;
      const float4 c0 = *(const float4*)&s_ctil[r*520 + lane*4];
      const float4 c1 = *(const float4*)&s_ctil[r*520 + 256 + lane*4];
      const float4* ewp = (const float4*)(ew + b*16);
      float er[16];
      #pragma unroll
      for (int j = 0; j < 4; ++j){
        float4 e = ewp[j];
        er[4*j]=e.x; er[4*j+1]=e.y; er[4*j+2]=e.z; er[4*j+3]=e.w;
      }
      float4 xv[16];
      const float* npt = nbr + ((b << 4) << 8) + lane*4;
      #pragma unroll
      for (int k = 0; k < 16; ++k) xv[k] = *(const float4*)(npt + (k << 8));
      float sum0 = 0.f, sum1 = 0.f;
      float4 agg0 = {0,0,0,0}, agg1 = {0,0,0,0};
      #pragma unroll
      for (int k = 0; k < 16; ++k){
        float p0 = xv[k].x*c0.x + xv[k].y*c0.y + xv[k].z*c0.z + xv[k].w*c0.w;
        float p1 = xv[k].x*c1.x + xv[k].y*c1.y + xv[k].z*c1.z + xv[k].w*c1.w;
        #pragma unroll
        for (int m = 32; m >= 1; m >>= 1){
          p0 += __shfl_xor(p0, m, 64);
          p1 += __shfl_xor(p1, m, 64);
        }
        const float w0 = __expf(p0*SCALE + er[k]);   // scores O(1): no max-sub needed
        const float w1 = __expf(p1*SCALE + er[k]);
        sum0 += w0; sum1 += w1;
        agg0.x += w0*xv[k].x; agg0.y += w0*xv[k].y; agg0.z += w0*xv[k].z; agg0.w += w0*xv[k].w;
        agg1.x += w1*xv[k].x; agg1.y += w1*xv[k].y; agg1.z += w1*xv[k].z; agg1.w += w1*xv[k].w;
      }
      const float i0 = 1.0f / sum0, i1 = 1.0f / sum1;
      float4 o0, o1;
      o0.x = agg0.x*i0; o0.y = agg0.y*i0; o0.z = agg0.z*i0; o0.w = agg0.w*i0;
      o1.x = agg1.x*i1; o1.y = agg1.y*i1; o1.z = agg1.z*i1; o1.w = agg1.w*i1;
      *(float4*)&s_ctil[r*520 + lane*4]       = o0;  // overwrite own row's ctil
      *(float4*)&s_ctil[r*520 + 256 + lane*4] = o1;
    }
  }
  __syncthreads();

  // ---- Phase C: ctx[16x256] = agg_h @ Wv_h^T (full-256 contraction/head) ----
  {
    for (int t = 0; t < 16; ++t){
      const int col = t*16 + tc;            // 0..255
      const int h   = col >> 7;             // head = output dim / 128
      const float* ap = &s_ctil[tr*520 + h*256];
      const float* wp = W2f + col*256;
      float acc = 0.f;
      #pragma unroll 8
      for (int e = 0; e < 256; e += 4){
        float4 av = *(const float4*)(ap + e);
        float4 wv = *(const float4*)(wp + e);
        acc += av.x*wv.x + av.y*wv.y + av.z*wv.z + av.w*wv.w;
      }
      s_c[tr*260 + col] = acc;              // ctx into s_c (center is dead)
    }
  }
  __syncthreads();

  // ---- Phase D: LayerNorm over 256 (fp32), ctx_n -> s_ctil[r][0..255] ----
  {
    #pragma unroll 1
    for (int rr = 0; rr < 4; ++rr){
      const int r = wid*4 + rr;
      const float4 x = *(const float4*)&s_c[r*260 + lane*4];
      float s = x.x + x.y + x.z + x.w;
      float q = x.x*x.x + x.y*x.y + x.z*x.z + x.w*x.w;
      #pragma unroll
      for (int m = 32; m >= 1; m >>= 1){
        s += __shfl_xor(s, m, 64);
        q += __shfl_xor(q, m, 64);
      }
      const float mu  = s * (1.f/256.f);
      const float var = q * (1.f/256.f) - mu*mu;
      const float rs  = rsqrtf(var + 1e-5f);
      const float4 g  = *(const float4*)(gamma + lane*4);
      const float4 bb = *(const float4*)(beta  + lane*4);
      float4 y;
      y.x = (x.x - mu)*rs*g.x + bb.x;
      y.y = (x.y - mu)*rs*g.y + bb.y;
      y.z = (x.z - mu)*rs*g.z + bb.z;
      y.w = (x.w - mu)*rs*g.w + bb.w;
      *(float4*)&s_ctil[r*520 + lane*4] = y;
    }
  }
  __syncthreads();

  // ---- Phase E: out-right[16x128] = ctx_n @ Wx^T ----
  {
    for (int t = 0; t < 8; ++t){
      const int col = t*16 + tc;            // 0..127
      const float* ap = &s_ctil[tr*520];
      const float* wp = W3f + col*256;
      float acc = 0.f;
      #pragma unroll 8
      for (int e = 0; e < 256; e += 4){
        float4 av = *(const float4*)(ap + e);
        float4 wv = *(const float4*)(wp + e);
        acc += av.x*wv.x + av.y*wv.y + av.z*wv.z + av.w*wv.w;
      }
      out[((long)(b0 + tr) << 8) + 128 + col] = acc;
    }
  }
}

extern "C" void kernel_launch(void* const* d_in, const int* in_sizes, int n_in,
                              void* d_out, int out_size, void* d_ws, size_t ws_size,
                              hipStream_t stream){
  const float* center = (const float*)d_in[0];
  const float* nbr    = (const float*)d_in[1];
  const float* ew     = (const float*)d_in[2];
  const float* Wq     = (const float*)d_in[3];
  const float* Wk     = (const float*)d_in[4];
  const float* Wv     = (const float*)d_in[5];
  const float* Wc     = (const float*)d_in[6];
  const float* Wx     = (const float*)d_in[7];
  const float* gamma  = (const float*)d_in[8];
  const float* beta   = (const float*)d_in[9];
  (void)in_sizes; (void)n_in; (void)out_size;

  float* W = (float*)d_ws;   // uses 1 MiB of workspace
  (void)ws_size;

  prep_kernel<<<1024, 256, 0, stream>>>(Wq, Wk, Wv, Wc, Wx, W);
  fused_kernel<<<Bsz/BR, 256, 0, stream>>>(center, nbr, ew, gamma, beta, W, (float*)d_out);
}

// Round 5
// 1012.854 us; speedup vs baseline: 3.5470x; 3.5470x over previous
//
#include <hip/hip_runtime.h>

// B=32768, K=16, D=256, H=2, HD=128
#define Bsz 32768
#define BR  16           // rows per block
#define SCALE 0.08838834764831845f   // 1/sqrt(128)

typedef __attribute__((ext_vector_type(4))) float f32x4;

// ---------------------------------------------------------------------------
// Prep: fp32 weights in ws, ALL K-MAJOR (transposed) for coalesced reads.
//   W1T f32 [256][640]: W1T[k][n] = M/Wc row n, element k
//       n 0..511  : M_h[k][m] = sum_d Wq[h*128+d][k]*Wk[h*128+d][m]  (n=h*256+m)
//       n 512..639: Wc[n-512][k]
//   W2T f32 [256][256]: W2T[k][c] = Wv[c][k]
//   W3T f32 [256][128]: W3T[k][c] = Wx[c][k]
// Total: (640+256+128)*256*4 = 1 MiB exactly.
// ---------------------------------------------------------------------------
__global__ void prep_kernel(const float* __restrict__ Wq, const float* __restrict__ Wk,
                            const float* __restrict__ Wv, const float* __restrict__ Wc,
                            const float* __restrict__ Wx, float* __restrict__ wsf){
  float* W1T = wsf;                  // [256][640]
  float* W2T = wsf + 256*640;        // [256][256]
  float* W3T = W2T + 256*256;        // [256][128]
  const int n = blockIdx.x;
  const int k = threadIdx.x;
  if (n < 512){
    const int h = n >> 8, m = n & 255;
    const float* wq = Wq + h*128*256 + k;   // column k (coalesced over k)
    const float* wk = Wk + h*128*256 + m;   // broadcast
    float s = 0.f;
    for (int d = 0; d < 128; ++d) s += wq[d*256] * wk[d*256];
    W1T[k*640 + n] = s;
  } else if (n < 640){
    W1T[k*640 + n] = Wc[(n-512)*256 + k];
  } else if (n < 896){
    const int r = n - 640;
    W2T[k*256 + r] = Wv[r*256 + k];
  } else {
    const int r = n - 896;
    W3T[k*128 + r] = Wx[r*256 + k];
  }
}

// ---------------------------------------------------------------------------
// Fused main kernel — ALL fp32 VALU (identical math to passing round 3),
// single change: A/C/E use k-major weights + coalesced column-block loads.
// 16 rows/block, 256 threads (4 waves).
// LDS: s_c    f32 [16][260]: center (stage..A), then ctx (C..D)
//      s_ctil f32 [16][520]: ctil (A..B), then agg (B..C), then ctx_n (D..E)
// Thread (tr,tc) = (tid>>4, tid&15) owns row tr, cols {64t + 4tc + j}.
// ---------------------------------------------------------------------------
__global__ __launch_bounds__(256, 3) void fused_kernel(
    const float* __restrict__ center, const float* __restrict__ nbr,
    const float* __restrict__ ew, const float* __restrict__ gamma,
    const float* __restrict__ beta, const float* __restrict__ Wall,
    float* __restrict__ out)
{
  __shared__ __align__(16) float s_c[BR*260];
  __shared__ __align__(16) float s_ctil[BR*520];

  const int tid  = threadIdx.x;
  const int wid  = tid >> 6;
  const int lane = tid & 63;
  const int b0   = blockIdx.x * BR;

  const float* W1T = Wall;               // [256][640]
  const float* W2T = Wall + 256*640;     // [256][256]
  const float* W3T = W2T + 256*256;      // [256][128]

  const int tr = tid >> 4;     // 0..15
  const int tc = tid & 15;     // 0..15

  // ---- stage center tile -> fp32 LDS (identical to round 3) ----
  {
    const float* cp = center + ((long)(b0 + tr) << 8) + tc*16;
    #pragma unroll
    for (int it = 0; it < 4; ++it)
      *(float4*)&s_c[tr*260 + tc*16 + it*4] = *(const float4*)(cp + it*4);
  }
  __syncthreads();

  // ---- Phase A: [16x256] @ [256x640] -> ctil (LDS) + out-left (global) ----
  {
    f32x4 acc[10];
    #pragma unroll
    for (int t = 0; t < 10; ++t) acc[t] = (f32x4){0.f,0.f,0.f,0.f};
    #pragma unroll 2
    for (int k = 0; k < 256; ++k){
      const float a = s_c[tr*260 + k];
      const f32x4* w = (const f32x4*)(W1T + k*640) + tc;
      #pragma unroll
      for (int t = 0; t < 10; ++t)
        acc[t] += a * w[t*16];
    }
    #pragma unroll
    for (int t = 0; t < 8; ++t)
      *(f32x4*)&s_ctil[tr*520 + t*64 + tc*4] = acc[t];
    float* op = out + ((long)(b0 + tr) << 8) + tc*4;
    *(f32x4*)(op)      = acc[8];    // out cols 0..63
    *(f32x4*)(op + 64) = acc[9];    // out cols 64..127
  }
  __syncthreads();

  // ---- Phase B: attention (byte-identical to round 3) ----
  {
    #pragma unroll 1
    for (int rr = 0; rr < 4; ++rr){
      const int r = wid*4 + rr;
      const long b = b0 + r;
      const float4 c0 = *(const float4*)&s_ctil[r*520 + lane*4];
      const float4 c1 = *(const float4*)&s_ctil[r*520 + 256 + lane*4];
      const float4* ewp = (const float4*)(ew + b*16);
      float er[16];
      #pragma unroll
      for (int j = 0; j < 4; ++j){
        float4 e = ewp[j];
        er[4*j]=e.x; er[4*j+1]=e.y; er[4*j+2]=e.z; er[4*j+3]=e.w;
      }
      float4 xv[16];
      const float* npt = nbr + ((b << 4) << 8) + lane*4;
      #pragma unroll
      for (int k = 0; k < 16; ++k) xv[k] = *(const float4*)(npt + (k << 8));
      float sum0 = 0.f, sum1 = 0.f;
      float4 agg0 = {0,0,0,0}, agg1 = {0,0,0,0};
      #pragma unroll
      for (int k = 0; k < 16; ++k){
        float p0 = xv[k].x*c0.x + xv[k].y*c0.y + xv[k].z*c0.z + xv[k].w*c0.w;
        float p1 = xv[k].x*c1.x + xv[k].y*c1.y + xv[k].z*c1.z + xv[k].w*c1.w;
        #pragma unroll
        for (int m = 32; m >= 1; m >>= 1){
          p0 += __shfl_xor(p0, m, 64);
          p1 += __shfl_xor(p1, m, 64);
        }
        const float w0 = __expf(p0*SCALE + er[k]);   // scores O(1): no max-sub needed
        const float w1 = __expf(p1*SCALE + er[k]);
        sum0 += w0; sum1 += w1;
        agg0.x += w0*xv[k].x; agg0.y += w0*xv[k].y; agg0.z += w0*xv[k].z; agg0.w += w0*xv[k].w;
        agg1.x += w1*xv[k].x; agg1.y += w1*xv[k].y; agg1.z += w1*xv[k].z; agg1.w += w1*xv[k].w;
      }
      const float i0 = 1.0f / sum0, i1 = 1.0f / sum1;
      float4 o0, o1;
      o0.x = agg0.x*i0; o0.y = agg0.y*i0; o0.z = agg0.z*i0; o0.w = agg0.w*i0;
      o1.x = agg1.x*i1; o1.y = agg1.y*i1; o1.z = agg1.z*i1; o1.w = agg1.w*i1;
      *(float4*)&s_ctil[r*520 + lane*4]       = o0;  // agg overwrites own row's ctil
      *(float4*)&s_ctil[r*520 + 256 + lane*4] = o1;
    }
  }
  __syncthreads();

  // ---- Phase C: ctx = agg_h @ Wv_h^T (coalesced k-major), ctx -> s_c ----
  {
    f32x4 ac0 = {0,0,0,0}, ac1 = {0,0,0,0}, ac2 = {0,0,0,0}, ac3 = {0,0,0,0};
    #pragma unroll 2
    for (int k = 0; k < 256; ++k){
      const float a0 = s_ctil[tr*520 + k];
      const float a1 = s_ctil[tr*520 + 256 + k];
      const f32x4* w = (const f32x4*)(W2T + (k << 8)) + tc;
      ac0 += a0 * w[0];       // cols   0.. 63  (head 0)
      ac1 += a0 * w[16];      // cols  64..127  (head 0)
      ac2 += a1 * w[32];      // cols 128..191  (head 1)
      ac3 += a1 * w[48];      // cols 192..255  (head 1)
    }
    *(f32x4*)&s_c[tr*260 +   0 + 4*tc] = ac0;
    *(f32x4*)&s_c[tr*260 +  64 + 4*tc] = ac1;
    *(f32x4*)&s_c[tr*260 + 128 + 4*tc] = ac2;
    *(f32x4*)&s_c[tr*260 + 192 + 4*tc] = ac3;
  }
  __syncthreads();

  // ---- Phase D: LayerNorm (byte-identical to round 3), ctx_n -> s_ctil ----
  {
    #pragma unroll 1
    for (int rr = 0; rr < 4; ++rr){
      const int r = wid*4 + rr;
      const float4 x = *(const float4*)&s_c[r*260 + lane*4];
      float s = x.x + x.y + x.z + x.w;
      float q = x.x*x.x + x.y*x.y + x.z*x.z + x.w*x.w;
      #pragma unroll
      for (int m = 32; m >= 1; m >>= 1){
        s += __shfl_xor(s, m, 64);
        q += __shfl_xor(q, m, 64);
      }
      const float mu  = s * (1.f/256.f);
      const float var = q * (1.f/256.f) - mu*mu;
      const float rs  = rsqrtf(var + 1e-5f);
      const float4 g  = *(const float4*)(gamma + lane*4);
      const float4 bb = *(const float4*)(beta  + lane*4);
      float4 y;
      y.x = (x.x - mu)*rs*g.x + bb.x;
      y.y = (x.y - mu)*rs*g.y + bb.y;
      y.z = (x.z - mu)*rs*g.z + bb.z;
      y.w = (x.w - mu)*rs*g.w + bb.w;
      *(float4*)&s_ctil[r*520 + lane*4] = y;
    }
  }
  __syncthreads();

  // ---- Phase E: out-right = ctx_n @ Wx^T (coalesced k-major) ----
  {
    f32x4 ac0 = {0,0,0,0}, ac1 = {0,0,0,0};
    #pragma unroll 2
    for (int k = 0; k < 256; ++k){
      const float a = s_ctil[tr*520 + k];
      const f32x4* w = (const f32x4*)(W3T + (k << 7)) + tc;
      ac0 += a * w[0];        // out cols 128..191
      ac1 += a * w[16];       // out cols 192..255
    }
    float* op = out + ((long)(b0 + tr) << 8) + 128 + 4*tc;
    *(f32x4*)(op)      = ac0;
    *(f32x4*)(op + 64) = ac1;
  }
}

extern "C" void kernel_launch(void* const* d_in, const int* in_sizes, int n_in,
                              void* d_out, int out_size, void* d_ws, size_t ws_size,
                              hipStream_t stream){
  const float* center = (const float*)d_in[0];
  const float* nbr    = (const float*)d_in[1];
  const float* ew     = (const float*)d_in[2];
  const float* Wq     = (const float*)d_in[3];
  const float* Wk     = (const float*)d_in[4];
  const float* Wv     = (const float*)d_in[5];
  const float* Wc     = (const float*)d_in[6];
  const float* Wx     = (const float*)d_in[7];
  const float* gamma  = (const float*)d_in[8];
  const float* beta   = (const float*)d_in[9];
  (void)in_sizes; (void)n_in; (void)out_size;

  float* W = (float*)d_ws;   // uses exactly 1 MiB of workspace
  (void)ws_size;

  prep_kernel<<<1024, 256, 0, stream>>>(Wq, Wk, Wv, Wc, Wx, W);
  fused_kernel<<<Bsz/BR, 256, 0, stream>>>(center, nbr, ew, gamma, beta, W, (float*)d_out);
}